// Round 4
// baseline (14072.595 us; speedup 1.0000x reference)
//
#include <hip/hip_runtime.h>
#include <math.h>

#define T_STEPS 1024
#define NB 128
#define D_IN 512
#define D_H 1024
#define K_TOT 1536
#define N_A 3072   // packed rows: [0,1024)=uW, [1024,2048)=gW_x, [2048,3072)=aW_x
#define N_H 2048   // packed rows: group g (j in [16g,16g+16)): 16 g-rows then 16 a-rows

typedef __bf16 bf16x8 __attribute__((ext_vector_type(8)));
typedef float f32x4 __attribute__((ext_vector_type(4)));

__device__ __forceinline__ unsigned short f2bf(float f) {
    unsigned int u = __float_as_uint(f);
    unsigned int r = 0x7fffu + ((u >> 16) & 1u);
    return (unsigned short)((u + r) >> 16);
}
__device__ __forceinline__ float bf2f(unsigned short v) {
    return __uint_as_float(((unsigned int)v) << 16);
}
__device__ __forceinline__ float fast_tanh(float x) {
    float ax = fabsf(x);
    float e = __expf(2.0f * ax);
    float t = 1.0f - 2.0f / (e + 1.0f);
    return copysignf(t, x);
}

// ---------------- one-time packing / init ----------------

__global__ __launch_bounds__(256) void pack_wa(
    const float* __restrict__ uW, const float* __restrict__ gW,
    const float* __restrict__ aW, unsigned short* __restrict__ wa) {
    int i = blockIdx.x * 256 + threadIdx.x;          // N_A * D_IN
    if (i >= N_A * D_IN) return;
    int rr = i >> 9, k = i & 511;
    float v;
    if (rr < 1024)       v = uW[(size_t)rr * D_IN + k];
    else if (rr < 2048)  v = gW[(size_t)(rr - 1024) * K_TOT + k];
    else                 v = aW[(size_t)(rr - 2048) * K_TOT + k];
    wa[i] = f2bf(v);
}

__global__ __launch_bounds__(256) void pack_wh(
    const float* __restrict__ gW, const float* __restrict__ aW,
    unsigned short* __restrict__ wh) {
    int i = blockIdx.x * 256 + threadIdx.x;          // N_H * D_H
    if (i >= N_H * D_H) return;
    int rr = i >> 10, k = i & 1023;
    int g = rr >> 5, ii = rr & 31, j = g * 16 + (ii & 15);
    const float* src = (ii < 16) ? gW : aW;
    wh[i] = f2bf(src[(size_t)j * K_TOT + D_IN + k]);
}

__global__ __launch_bounds__(256) void rwa_init(
    const float* __restrict__ init_st, float* __restrict__ nbuf,
    float* __restrict__ dbuf, unsigned short* __restrict__ hbuf,
    int* __restrict__ flags) {
    int i = blockIdx.x * 256 + threadIdx.x;          // NB * D_H
    if (i >= NB * D_H) return;
    nbuf[i] = 0.f; dbuf[i] = 0.f;
    hbuf[i] = f2bf(tanhf(init_st[i & (D_H - 1)]));   // parity-0 buffer
    if (i < 256) flags[i] = 0;
}

// ---------------- phase A: pre = bf16( x_chunk @ W_A^T + bias ) ----------------

__global__ __launch_bounds__(256) void phase_a(
    const float* __restrict__ x, const unsigned short* __restrict__ wa,
    const float* __restrict__ ub, const float* __restrict__ gb,
    unsigned short* __restrict__ pre)
{
    __shared__ unsigned short As[128][72];
    __shared__ unsigned short Bs[128][72];
    const int tid = threadIdx.x;
    const int bn = blockIdx.x;           // 0..23
    const int bm = blockIdx.y;           // 0..CT-1
    const int wave = tid >> 6, lane = tid & 63;
    const int wm = wave >> 1, wn = wave & 1;
    const int lr = lane & 15, lk = lane >> 4;

    f32x4 acc[4][4] = {};

    for (int k0 = 0; k0 < D_IN; k0 += 64) {
        for (int i = tid; i < 128 * 16; i += 256) {       // A: f32->bf16
            int r = i >> 4, c4 = (i & 15) * 4;
            float4 v = *(const float4*)&x[(size_t)(bm * 128 + r) * D_IN + k0 + c4];
            unsigned short* d = &As[r][c4];
            d[0] = f2bf(v.x); d[1] = f2bf(v.y); d[2] = f2bf(v.z); d[3] = f2bf(v.w);
        }
        for (int i = tid; i < 128 * 8; i += 256) {        // B: 16B each
            int r = i >> 3, c8 = (i & 7) * 8;
            *(uint4*)&Bs[r][c8] =
                *(const uint4*)&wa[(size_t)(bn * 128 + r) * D_IN + k0 + c8];
        }
        __syncthreads();
        #pragma unroll
        for (int ks = 0; ks < 2; ++ks) {
            bf16x8 af[4], bfr[4];
            #pragma unroll
            for (int mf = 0; mf < 4; ++mf)
                af[mf] = *(const bf16x8*)&As[wm * 64 + mf * 16 + lr][ks * 32 + lk * 8];
            #pragma unroll
            for (int nf = 0; nf < 4; ++nf)
                bfr[nf] = *(const bf16x8*)&Bs[wn * 64 + nf * 16 + lr][ks * 32 + lk * 8];
            #pragma unroll
            for (int mf = 0; mf < 4; ++mf)
                #pragma unroll
                for (int nf = 0; nf < 4; ++nf)
                    acc[mf][nf] = __builtin_amdgcn_mfma_f32_16x16x32_bf16(
                        af[mf], bfr[nf], acc[mf][nf], 0, 0, 0);
        }
        __syncthreads();
    }

    #pragma unroll
    for (int nf = 0; nf < 4; ++nf) {
        int n = bn * 128 + wn * 64 + nf * 16 + lr;
        float bias = (n < 1024) ? ub[n] : ((n < 2048) ? gb[n - 1024] : 0.f);
        #pragma unroll
        for (int mf = 0; mf < 4; ++mf) {
            int mbase = bm * 128 + wm * 64 + mf * 16 + lk * 4;
            #pragma unroll
            for (int r = 0; r < 4; ++r)
                pre[(size_t)(mbase + r) * N_A + n] = f2bf(acc[mf][nf][r] + bias);
        }
    }
}

// ---------------- persistent recurrence kernel ----------------
// 256 blocks (1/CU): bn = bid>>2 (j-group of 16), bm = bid&3 (32 batch rows).
// wh tile resident in LDS for all steps; n/d in registers; steps separated by
// per-bm producer counters (agent-scope release/acquire).

__global__ __launch_bounds__(512, 2) void rwa_persist(
    const unsigned short* __restrict__ wh,    // [2048][1024] bf16
    const unsigned short* __restrict__ pre,   // [nt*128][3072] bf16 (this chunk)
    unsigned short* __restrict__ hbuf,        // [2][128][1024] bf16
    float* __restrict__ nbuf, float* __restrict__ dbuf,
    float* __restrict__ out,
    int* __restrict__ flags,                  // flags[bm*64]
    int t0, int nt)
{
    __shared__ unsigned short whs[32][1024];  // 64 KB, resident weights
    __shared__ unsigned short hs[32][1024];   // 64 KB, h staging
    __shared__ float scr[6 * 512];            // 12 KB, k-split reduction

    const int tid = threadIdx.x;
    const int bid = blockIdx.x;
    const int bn = bid >> 2;      // 0..63
    const int bm = bid & 3;       // 0..3
    const int wave = tid >> 6, lane = tid & 63;
    const int wm = wave >> 2;     // 0..1
    const int kq = wave & 3;      // 0..3
    const int lr = lane & 15, lk = lane >> 4;

    // --- load wh tile once (swizzled granules) ---
    for (int s = tid; s < 4096; s += 512) {
        int r = s >> 7, g = s & 127;
        uint4 v = *(const uint4*)&wh[(size_t)(bn * 32 + r) * 1024 + (size_t)g * 8];
        *(uint4*)&whs[r][(g ^ (r & 7)) * 8] = v;
    }

    // --- persistent n/d registers (kq==0 threads own 4 (b,j) pairs) ---
    const int j = bn * 16 + lr;
    float nr[4], dr[4];
    if (kq == 0) {
        #pragma unroll
        for (int r = 0; r < 4; ++r) {
            int b = bm * 32 + wm * 16 + lk * 4 + r;
            size_t idx = (size_t)b * D_H + j;
            nr[r] = nbuf[idx]; dr[r] = dbuf[idx];
        }
    }
    __syncthreads();

    for (int l = 0; l < nt; ++l) {
        const int t = t0 + l;

        if (t > 0) {
            if (tid == 0) {
                const int target = t * 64;
                while (__hip_atomic_load(&flags[bm * 64], __ATOMIC_RELAXED,
                                         __HIP_MEMORY_SCOPE_AGENT) < target)
                    __builtin_amdgcn_s_sleep(2);
                // one acquire to publish producers' writes to this block
                (void)__hip_atomic_load(&flags[bm * 64], __ATOMIC_ACQUIRE,
                                        __HIP_MEMORY_SCOPE_AGENT);
            }
            __syncthreads();
        }

        // --- stage h (bm slice) into LDS, swizzled ---
        const unsigned short* hsrc =
            hbuf + ((size_t)(t & 1) * NB + bm * 32) * D_H;
        for (int s = tid; s < 4096; s += 512) {
            int r = s >> 7, g = s & 127;
            uint4 v = *(const uint4*)&hsrc[(size_t)r * D_H + (size_t)g * 8];
            *(uint4*)&hs[r][(g ^ (r & 7)) * 8] = v;
        }
        __syncthreads();

        // --- MFMA: wave kq covers K slice [kq*256, kq*256+256) ---
        f32x4 accg = {}, acca = {};
        const int ar = wm * 16 + lr;
        #pragma unroll
        for (int ks = 0; ks < 8; ++ks) {
            const int k = kq * 256 + ks * 32 + lk * 8;
            const int gidx = k >> 3;
            bf16x8 av = *(const bf16x8*)&hs[ar][(gidx ^ (ar & 7)) << 3];
            bf16x8 bg = *(const bf16x8*)&whs[lr][(gidx ^ (lr & 7)) << 3];
            bf16x8 ba = *(const bf16x8*)&whs[16 + lr][(gidx ^ (lr & 7)) << 3];
            accg = __builtin_amdgcn_mfma_f32_16x16x32_bf16(av, bg, accg, 0, 0, 0);
            acca = __builtin_amdgcn_mfma_f32_16x16x32_bf16(av, ba, acca, 0, 0, 0);
        }
        __syncthreads();

        // --- cross-wave K reduction ---
        if (kq != 0) {
            int base = (wm * 3 + (kq - 1)) * 512 + lane * 4;
            *(f32x4*)&scr[base]       = accg;
            *(f32x4*)&scr[base + 256] = acca;
        }
        __syncthreads();

        if (kq == 0) {
            #pragma unroll
            for (int s = 0; s < 3; ++s) {
                int base = (wm * 3 + s) * 512 + lane * 4;
                accg += *(const f32x4*)&scr[base];
                acca += *(const f32x4*)&scr[base + 256];
            }
            unsigned short* hdst = hbuf + (size_t)((t + 1) & 1) * NB * D_H;
            #pragma unroll
            for (int r = 0; r < 4; ++r) {
                int b = bm * 32 + wm * 16 + lk * 4 + r;
                size_t pb = (size_t)(l * 128 + b) * N_A;
                float u  = bf2f(pre[pb + j]);
                float gx = bf2f(pre[pb + 1024 + j]);
                float ax = bf2f(pre[pb + 2048 + j]);
                float g = gx + accg[r];
                float a = ax + acca[r];
                float ea = __expf(a);
                float z = u * fast_tanh(g);
                nr[r] += z * ea;
                dr[r] += ea;
                float h = fast_tanh(nr[r] / dr[r]);
                size_t idx = (size_t)b * D_H + j;
                out[(size_t)t * NB * D_H + idx] = h;
                hdst[idx] = f2bf(h);
                if (t == T_STEPS - 1) out[(size_t)T_STEPS * NB * D_H + idx] = h;
            }
        }
        __syncthreads();   // drain all epilogue writes (vmcnt(0) at barrier)

        if (tid == 0)
            __hip_atomic_fetch_add(&flags[bm * 64], 1, __ATOMIC_RELEASE,
                                   __HIP_MEMORY_SCOPE_AGENT);
    }

    // --- chunk end: spill n/d ---
    if (kq == 0) {
        #pragma unroll
        for (int r = 0; r < 4; ++r) {
            int b = bm * 32 + wm * 16 + lk * 4 + r;
            size_t idx = (size_t)b * D_H + j;
            nbuf[idx] = nr[r]; dbuf[idx] = dr[r];
        }
    }
}

// ---------------- launch ----------------

extern "C" void kernel_launch(void* const* d_in, const int* in_sizes, int n_in,
                              void* d_out, int out_size, void* d_ws, size_t ws_size,
                              hipStream_t stream) {
    const float* x       = (const float*)d_in[0];
    const float* init_st = (const float*)d_in[1];
    const float* uW      = (const float*)d_in[2];
    const float* ub      = (const float*)d_in[3];
    const float* gW      = (const float*)d_in[4];
    const float* gb      = (const float*)d_in[5];
    const float* aW      = (const float*)d_in[6];
    float* out = (float*)d_out;

    char* ws = (char*)d_ws;
    float* nbuf = (float*)ws;                                   ws += (size_t)NB * D_H * 4;
    float* dbuf = (float*)ws;                                   ws += (size_t)NB * D_H * 4;
    unsigned short* hbuf = (unsigned short*)ws;                 ws += (size_t)2 * NB * D_H * 2;
    int* flags = (int*)ws;                                      ws += 256 * 4;
    unsigned short* wa = (unsigned short*)ws;                   ws += (size_t)N_A * D_IN * 2;
    unsigned short* wh = (unsigned short*)ws;                   ws += (size_t)N_H * D_H * 2;
    unsigned short* pre = (unsigned short*)ws;
    size_t fixed = (size_t)(ws - (char*)d_ws);
    size_t per_ct = (size_t)128 * N_A * 2;                      // 768 KB per step slot

    int CT = 1024;
    while (CT > 1 && fixed + (size_t)CT * per_ct > ws_size) CT >>= 1;

    pack_wa<<<(N_A * D_IN + 255) / 256, 256, 0, stream>>>(uW, gW, aW, wa);
    pack_wh<<<(N_H * D_H + 255) / 256, 256, 0, stream>>>(gW, aW, wh);
    rwa_init<<<(NB * D_H + 255) / 256, 256, 0, stream>>>(init_st, nbuf, dbuf, hbuf, flags);

    for (int c = 0; c < T_STEPS / CT; ++c) {
        phase_a<<<dim3(24, CT), 256, 0, stream>>>(
            x + (size_t)c * CT * NB * D_IN, wa, ub, gb, pre);
        rwa_persist<<<256, 512, 0, stream>>>(
            wh, pre, hbuf, nbuf, dbuf, out, flags, c * CT, CT);
    }
}

// Round 5
// 9063.575 us; speedup vs baseline: 1.5527x; 1.5527x over previous
//
#include <hip/hip_runtime.h>
#include <math.h>

#define T_STEPS 1024
#define NB 128
#define D_IN 512
#define D_H 1024
#define K_TOT 1536
#define N_A 3072   // packed rows: [0,1024)=uW, [1024,2048)=gW_x, [2048,3072)=aW_x
#define N_H 2048   // packed rows: group g (j in [16g,16g+16)): 16 g-rows then 16 a-rows

typedef __bf16 bf16x8 __attribute__((ext_vector_type(8)));
typedef float f32x4 __attribute__((ext_vector_type(4)));
typedef unsigned long long u64;

__device__ __forceinline__ unsigned short f2bf(float f) {
    unsigned int u = __float_as_uint(f);
    unsigned int r = 0x7fffu + ((u >> 16) & 1u);
    return (unsigned short)((u + r) >> 16);
}
__device__ __forceinline__ float bf2f(unsigned short v) {
    return __uint_as_float(((unsigned int)v) << 16);
}
__device__ __forceinline__ float fast_tanh(float x) {
    float ax = fabsf(x);
    float e = __expf(2.0f * ax);
    float t = 1.0f - 2.0f / (e + 1.0f);
    return copysignf(t, x);
}

// ---------------- one-time packing / init ----------------

__global__ __launch_bounds__(256) void pack_wa(
    const float* __restrict__ uW, const float* __restrict__ gW,
    const float* __restrict__ aW, unsigned short* __restrict__ wa) {
    int i = blockIdx.x * 256 + threadIdx.x;          // N_A * D_IN
    if (i >= N_A * D_IN) return;
    int rr = i >> 9, k = i & 511;
    float v;
    if (rr < 1024)       v = uW[(size_t)rr * D_IN + k];
    else if (rr < 2048)  v = gW[(size_t)(rr - 1024) * K_TOT + k];
    else                 v = aW[(size_t)(rr - 2048) * K_TOT + k];
    wa[i] = f2bf(v);
}

__global__ __launch_bounds__(256) void pack_wh(
    const float* __restrict__ gW, const float* __restrict__ aW,
    unsigned short* __restrict__ wh) {
    int i = blockIdx.x * 256 + threadIdx.x;          // N_H * D_H
    if (i >= N_H * D_H) return;
    int rr = i >> 10, k = i & 1023;
    int g = rr >> 5, ii = rr & 31, j = g * 16 + (ii & 15);
    const float* src = (ii < 16) ? gW : aW;
    wh[i] = f2bf(src[(size_t)j * K_TOT + D_IN + k]);
}

__global__ __launch_bounds__(256) void rwa_init(
    const float* __restrict__ init_st, float* __restrict__ nbuf,
    float* __restrict__ dbuf, unsigned short* __restrict__ hbuf,
    int* __restrict__ flags) {
    int i = blockIdx.x * 256 + threadIdx.x;          // NB * D_H
    if (i >= NB * D_H) return;
    nbuf[i] = 0.f; dbuf[i] = 0.f;
    hbuf[i] = f2bf(tanhf(init_st[i & (D_H - 1)]));   // parity-0 buffer
    if (i < 256) flags[i] = 0;
}

// ---------------- phase A: pre_t = bf16( x_chunk @ W_A^T + bias ) ----------------
// output layout TRANSPOSED per step: pre[tl][n=3072][b=128] bf16

__global__ __launch_bounds__(256) void phase_a(
    const float* __restrict__ x, const unsigned short* __restrict__ wa,
    const float* __restrict__ ub, const float* __restrict__ gb,
    unsigned short* __restrict__ pre)
{
    __shared__ unsigned short As[128][72];
    __shared__ unsigned short Bs[128][72];
    const int tid = threadIdx.x;
    const int bn = blockIdx.x;           // 0..23
    const int bm = blockIdx.y;           // 0..CT-1
    const int wave = tid >> 6, lane = tid & 63;
    const int wm = wave >> 1, wn = wave & 1;
    const int lr = lane & 15, lk = lane >> 4;

    f32x4 acc[4][4] = {};

    for (int k0 = 0; k0 < D_IN; k0 += 64) {
        for (int i = tid; i < 128 * 16; i += 256) {       // A: f32->bf16
            int r = i >> 4, c4 = (i & 15) * 4;
            float4 v = *(const float4*)&x[(size_t)(bm * 128 + r) * D_IN + k0 + c4];
            unsigned short* d = &As[r][c4];
            d[0] = f2bf(v.x); d[1] = f2bf(v.y); d[2] = f2bf(v.z); d[3] = f2bf(v.w);
        }
        for (int i = tid; i < 128 * 8; i += 256) {        // B: 16B each
            int r = i >> 3, c8 = (i & 7) * 8;
            *(uint4*)&Bs[r][c8] =
                *(const uint4*)&wa[(size_t)(bn * 128 + r) * D_IN + k0 + c8];
        }
        __syncthreads();
        #pragma unroll
        for (int ks = 0; ks < 2; ++ks) {
            bf16x8 af[4], bfr[4];
            #pragma unroll
            for (int mf = 0; mf < 4; ++mf)
                af[mf] = *(const bf16x8*)&As[wm * 64 + mf * 16 + lr][ks * 32 + lk * 8];
            #pragma unroll
            for (int nf = 0; nf < 4; ++nf)
                bfr[nf] = *(const bf16x8*)&Bs[wn * 64 + nf * 16 + lr][ks * 32 + lk * 8];
            #pragma unroll
            for (int mf = 0; mf < 4; ++mf)
                #pragma unroll
                for (int nf = 0; nf < 4; ++nf)
                    acc[mf][nf] = __builtin_amdgcn_mfma_f32_16x16x32_bf16(
                        af[mf], bfr[nf], acc[mf][nf], 0, 0, 0);
        }
        __syncthreads();
    }

    #pragma unroll
    for (int nf = 0; nf < 4; ++nf) {
        int n = bn * 128 + wn * 64 + nf * 16 + lr;
        float bias = (n < 1024) ? ub[n] : ((n < 2048) ? gb[n - 1024] : 0.f);
        #pragma unroll
        for (int mf = 0; mf < 4; ++mf) {
            int mbase = bm * 128 + wm * 64 + mf * 16 + lk * 4;
            #pragma unroll
            for (int r = 0; r < 4; ++r) {
                int mrow = mbase + r;
                pre[((size_t)(mrow >> 7) * N_A + n) * 128 + (mrow & 127)] =
                    f2bf(acc[mf][nf][r] + bias);
            }
        }
    }
}

// ---------------- persistent recurrence kernel ----------------
// 256 blocks (1/CU): bn = bid>>2 (j-group of 16), bm = bid&3 (32 batch rows).
// wh resident in LDS; n/d in registers; h + flags exchanged at the L3
// coherence point via sc0/sc1 ops — NO full-L2 wbl2/inv in the loop.

__global__ __launch_bounds__(512) void rwa_persist(
    const unsigned short* __restrict__ wh,    // [2048][1024] bf16
    const unsigned short* __restrict__ pre,   // [nt][3072][128] bf16 (this chunk)
    unsigned short* __restrict__ hbuf,        // [2][128][1024] bf16
    float* __restrict__ nbuf, float* __restrict__ dbuf,
    float* __restrict__ out,
    int* __restrict__ flags,                  // flags[bm*64]
    int t0, int nt)
{
    __shared__ unsigned short whs[32][1024];  // 64 KB, resident weights
    __shared__ unsigned short hs[32][1024];   // 64 KB, h staging
    __shared__ float scr[6 * 512];            // 12 KB, k-split reduction

    const int tid = threadIdx.x;
    const int bid = blockIdx.x;
    const int bn = bid >> 2;      // 0..63
    const int bm = bid & 3;       // 0..3
    const int wave = tid >> 6, lane = tid & 63;
    const int wm = wave >> 2;     // 0..1
    const int kq = wave & 3;      // 0..3
    const int lr = lane & 15, lk = lane >> 4;

    // --- load wh tile once (swizzled granules; kernel-boundary coherence ok) ---
    for (int s = tid; s < 4096; s += 512) {
        int r = s >> 7, g = s & 127;
        uint4 v = *(const uint4*)&wh[(size_t)(bn * 32 + r) * 1024 + (size_t)g * 8];
        *(uint4*)&whs[r][(g ^ (r & 7)) * 8] = v;
    }

    const int j = bn * 16 + lr;
    const int bbase = bm * 32 + wm * 16 + lk * 4;
    float nr[4], dr[4];
    if (kq == 0) {
        #pragma unroll
        for (int r = 0; r < 4; ++r) {
            size_t idx = (size_t)(bbase + r) * D_H + j;
            nr[r] = nbuf[idx]; dr[r] = dbuf[idx];
        }
    }
    __syncthreads();

    for (int l = 0; l < nt; ++l) {
        const int t = t0 + l;

        // --- prefetch this step's pre (independent of h; hides HBM latency) ---
        u64 puL = 0, pgL = 0, paL = 0;
        if (kq == 0) {
            size_t pb = (size_t)l * N_A * 128;
            puL = *(const u64*)&pre[pb + ((size_t)j) * 128 + bbase];
            pgL = *(const u64*)&pre[pb + ((size_t)(1024 + j)) * 128 + bbase];
            paL = *(const u64*)&pre[pb + ((size_t)(2048 + j)) * 128 + bbase];
        }

        // --- wait for all producers of step t-1 (point ops at L3, no cache flush) ---
        if (t > 0) {
            if (tid == 0) {
                const int target = t * 64;
                while (__hip_atomic_load(&flags[bm * 64], __ATOMIC_RELAXED,
                                         __HIP_MEMORY_SCOPE_SYSTEM) < target)
                    __builtin_amdgcn_s_sleep(2);
            }
            __syncthreads();
        }

        // --- stage h (bm slice) into LDS via L3-coherent loads, swizzled ---
        const unsigned short* hsrc =
            hbuf + ((size_t)(t & 1) * NB + bm * 32) * D_H;
        for (int s = tid; s < 8192; s += 512) {
            int r = s >> 8, g2 = s & 255;
            u64 v = __hip_atomic_load(
                (const u64*)(hsrc + (size_t)r * D_H) + g2,
                __ATOMIC_RELAXED, __HIP_MEMORY_SCOPE_SYSTEM);
            int g = g2 >> 1;
            *(u64*)&hs[r][((g ^ (r & 7)) << 3) + ((g2 & 1) << 2)] = v;
        }
        __syncthreads();

        // --- MFMA: wave kq covers K slice [kq*256, kq*256+256) ---
        f32x4 accg = {}, acca = {};
        const int ar = wm * 16 + lr;
        #pragma unroll
        for (int ks = 0; ks < 8; ++ks) {
            const int k = kq * 256 + ks * 32 + lk * 8;
            const int gidx = k >> 3;
            bf16x8 av = *(const bf16x8*)&hs[ar][(gidx ^ (ar & 7)) << 3];
            bf16x8 bg = *(const bf16x8*)&whs[lr][(gidx ^ (lr & 7)) << 3];
            bf16x8 ba = *(const bf16x8*)&whs[16 + lr][(gidx ^ (lr & 7)) << 3];
            accg = __builtin_amdgcn_mfma_f32_16x16x32_bf16(av, bg, accg, 0, 0, 0);
            acca = __builtin_amdgcn_mfma_f32_16x16x32_bf16(av, ba, acca, 0, 0, 0);
        }
        __syncthreads();

        // --- cross-wave K reduction ---
        if (kq != 0) {
            int base = (wm * 3 + (kq - 1)) * 512 + lane * 4;
            *(f32x4*)&scr[base]       = accg;
            *(f32x4*)&scr[base + 256] = acca;
        }
        __syncthreads();

        if (kq == 0) {
            #pragma unroll
            for (int s = 0; s < 3; ++s) {
                int base = (wm * 3 + s) * 512 + lane * 4;
                accg += *(const f32x4*)&scr[base];
                acca += *(const f32x4*)&scr[base + 256];
            }
            unsigned short* hdst = hbuf + (size_t)((t + 1) & 1) * NB * D_H;
            #pragma unroll
            for (int r = 0; r < 4; ++r) {
                int b = bbase + r;
                float u  = bf2f((unsigned short)(puL >> (16 * r)));
                float gx = bf2f((unsigned short)(pgL >> (16 * r)));
                float ax = bf2f((unsigned short)(paL >> (16 * r)));
                float g = gx + accg[r];
                float a = ax + acca[r];
                float ea = __expf(a);
                float z = u * fast_tanh(g);
                nr[r] += z * ea;
                dr[r] += ea;
                float h = fast_tanh(nr[r] / dr[r]);
                size_t idx = (size_t)b * D_H + j;
                out[(size_t)t * NB * D_H + idx] = h;
                if (t == T_STEPS - 1) out[(size_t)T_STEPS * NB * D_H + idx] = h;
                // pack h pair (j even|odd) and store L3-coherent
                unsigned int hb = f2bf(h);
                unsigned int ob = (unsigned int)__shfl_xor((int)hb, 1);
                if (!(lr & 1)) {
                    unsigned int packed = (hb & 0xffffu) | (ob << 16);
                    unsigned short* hp = hdst + idx;
                    asm volatile("global_store_dword %0, %1, off sc0 sc1"
                                 :: "v"(hp), "v"(packed) : "memory");
                }
            }
        }
        __syncthreads();   // vmcnt(0) drain: all h stores visible at L3

        if (tid == 0)
            __hip_atomic_fetch_add(&flags[bm * 64], 1, __ATOMIC_RELAXED,
                                   __HIP_MEMORY_SCOPE_SYSTEM);
    }

    if (kq == 0) {
        #pragma unroll
        for (int r = 0; r < 4; ++r) {
            size_t idx = (size_t)(bbase + r) * D_H + j;
            nbuf[idx] = nr[r]; dbuf[idx] = dr[r];
        }
    }
}

// ---------------- launch ----------------

extern "C" void kernel_launch(void* const* d_in, const int* in_sizes, int n_in,
                              void* d_out, int out_size, void* d_ws, size_t ws_size,
                              hipStream_t stream) {
    const float* x       = (const float*)d_in[0];
    const float* init_st = (const float*)d_in[1];
    const float* uW      = (const float*)d_in[2];
    const float* ub      = (const float*)d_in[3];
    const float* gW      = (const float*)d_in[4];
    const float* gb      = (const float*)d_in[5];
    const float* aW      = (const float*)d_in[6];
    float* out = (float*)d_out;

    char* ws = (char*)d_ws;
    float* nbuf = (float*)ws;                                   ws += (size_t)NB * D_H * 4;
    float* dbuf = (float*)ws;                                   ws += (size_t)NB * D_H * 4;
    unsigned short* hbuf = (unsigned short*)ws;                 ws += (size_t)2 * NB * D_H * 2;
    int* flags = (int*)ws;                                      ws += 256 * 4;
    unsigned short* wa = (unsigned short*)ws;                   ws += (size_t)N_A * D_IN * 2;
    unsigned short* wh = (unsigned short*)ws;                   ws += (size_t)N_H * D_H * 2;
    unsigned short* pre = (unsigned short*)ws;
    size_t fixed = (size_t)(ws - (char*)d_ws);
    size_t per_ct = (size_t)128 * N_A * 2;                      // 768 KB per step slot

    int CT = 1024;
    while (CT > 1 && fixed + (size_t)CT * per_ct > ws_size) CT >>= 1;

    pack_wa<<<(N_A * D_IN + 255) / 256, 256, 0, stream>>>(uW, gW, aW, wa);
    pack_wh<<<(N_H * D_H + 255) / 256, 256, 0, stream>>>(gW, aW, wh);
    rwa_init<<<(NB * D_H + 255) / 256, 256, 0, stream>>>(init_st, nbuf, dbuf, hbuf, flags);

    for (int c = 0; c < T_STEPS / CT; ++c) {
        phase_a<<<dim3(24, CT), 256, 0, stream>>>(
            x + (size_t)c * CT * NB * D_IN, wa, ub, gb, pre);
        rwa_persist<<<256, 512, 0, stream>>>(
            wh, pre, hbuf, nbuf, dbuf, out, flags, c * CT, CT);
    }
}

// Round 6
// 6065.334 us; speedup vs baseline: 2.3202x; 1.4943x over previous
//
#include <hip/hip_runtime.h>
#include <math.h>

#define T_STEPS 1024
#define NB 128
#define D_IN 512
#define D_H 1024
#define K_TOT 1536
#define N_A 3072   // packed rows: [0,1024)=uW, [1024,2048)=gW_x, [2048,3072)=aW_x
#define N_H 2048   // packed rows: group g (j in [16g,16g+16)): 16 g-rows then 16 a-rows

typedef __bf16 bf16x8 __attribute__((ext_vector_type(8)));
typedef float f32x4 __attribute__((ext_vector_type(4)));
typedef unsigned long long u64;

__device__ __forceinline__ unsigned short f2bf(float f) {
    unsigned int u = __float_as_uint(f);
    unsigned int r = 0x7fffu + ((u >> 16) & 1u);
    return (unsigned short)((u + r) >> 16);
}
__device__ __forceinline__ float bf2f(unsigned short v) {
    return __uint_as_float(((unsigned int)v) << 16);
}
__device__ __forceinline__ float fast_tanh(float x) {
    float ax = fabsf(x);
    float e = __expf(2.0f * ax);
    float t = 1.0f - 2.0f / (e + 1.0f);
    return copysignf(t, x);
}

// ---------------- one-time packing / init ----------------

__global__ __launch_bounds__(256) void pack_wa(
    const float* __restrict__ uW, const float* __restrict__ gW,
    const float* __restrict__ aW, unsigned short* __restrict__ wa) {
    int i = blockIdx.x * 256 + threadIdx.x;          // N_A * D_IN
    if (i >= N_A * D_IN) return;
    int rr = i >> 9, k = i & 511;
    float v;
    if (rr < 1024)       v = uW[(size_t)rr * D_IN + k];
    else if (rr < 2048)  v = gW[(size_t)(rr - 1024) * K_TOT + k];
    else                 v = aW[(size_t)(rr - 2048) * K_TOT + k];
    wa[i] = f2bf(v);
}

__global__ __launch_bounds__(256) void pack_wh(
    const float* __restrict__ gW, const float* __restrict__ aW,
    unsigned short* __restrict__ wh) {
    int i = blockIdx.x * 256 + threadIdx.x;          // N_H * D_H
    if (i >= N_H * D_H) return;
    int rr = i >> 10, k = i & 1023;
    int g = rr >> 5, ii = rr & 31, j = g * 16 + (ii & 15);
    const float* src = (ii < 16) ? gW : aW;
    wh[i] = f2bf(src[(size_t)j * K_TOT + D_IN + k]);
}

__global__ __launch_bounds__(256) void rwa_init(
    const float* __restrict__ init_st, float* __restrict__ nbuf,
    float* __restrict__ dbuf, unsigned short* __restrict__ hbuf,
    int* __restrict__ flags) {
    int i = blockIdx.x * 256 + threadIdx.x;          // NB * D_H
    if (i >= NB * D_H) return;
    nbuf[i] = 0.f; dbuf[i] = 0.f;
    hbuf[i] = f2bf(tanhf(init_st[i & (D_H - 1)]));   // parity-0 buffer
    if (i < 256) flags[i] = 0;
}

// ---------------- phase A: pre_t = bf16( x_chunk @ W_A^T + bias ) ----------------
// output layout TRANSPOSED per step: pre[tl][n=3072][b=128] bf16

__global__ __launch_bounds__(256) void phase_a(
    const float* __restrict__ x, const unsigned short* __restrict__ wa,
    const float* __restrict__ ub, const float* __restrict__ gb,
    unsigned short* __restrict__ pre)
{
    __shared__ unsigned short As[128][72];
    __shared__ unsigned short Bs[128][72];
    const int tid = threadIdx.x;
    const int bn = blockIdx.x;           // 0..23
    const int bm = blockIdx.y;           // 0..CT-1
    const int wave = tid >> 6, lane = tid & 63;
    const int wm = wave >> 1, wn = wave & 1;
    const int lr = lane & 15, lk = lane >> 4;

    f32x4 acc[4][4] = {};

    for (int k0 = 0; k0 < D_IN; k0 += 64) {
        for (int i = tid; i < 128 * 16; i += 256) {       // A: f32->bf16
            int r = i >> 4, c4 = (i & 15) * 4;
            float4 v = *(const float4*)&x[(size_t)(bm * 128 + r) * D_IN + k0 + c4];
            unsigned short* d = &As[r][c4];
            d[0] = f2bf(v.x); d[1] = f2bf(v.y); d[2] = f2bf(v.z); d[3] = f2bf(v.w);
        }
        for (int i = tid; i < 128 * 8; i += 256) {        // B: 16B each
            int r = i >> 3, c8 = (i & 7) * 8;
            *(uint4*)&Bs[r][c8] =
                *(const uint4*)&wa[(size_t)(bn * 128 + r) * D_IN + k0 + c8];
        }
        __syncthreads();
        #pragma unroll
        for (int ks = 0; ks < 2; ++ks) {
            bf16x8 af[4], bfr[4];
            #pragma unroll
            for (int mf = 0; mf < 4; ++mf)
                af[mf] = *(const bf16x8*)&As[wm * 64 + mf * 16 + lr][ks * 32 + lk * 8];
            #pragma unroll
            for (int nf = 0; nf < 4; ++nf)
                bfr[nf] = *(const bf16x8*)&Bs[wn * 64 + nf * 16 + lr][ks * 32 + lk * 8];
            #pragma unroll
            for (int mf = 0; mf < 4; ++mf)
                #pragma unroll
                for (int nf = 0; nf < 4; ++nf)
                    acc[mf][nf] = __builtin_amdgcn_mfma_f32_16x16x32_bf16(
                        af[mf], bfr[nf], acc[mf][nf], 0, 0, 0);
        }
        __syncthreads();
    }

    #pragma unroll
    for (int nf = 0; nf < 4; ++nf) {
        int n = bn * 128 + wn * 64 + nf * 16 + lr;
        float bias = (n < 1024) ? ub[n] : ((n < 2048) ? gb[n - 1024] : 0.f);
        #pragma unroll
        for (int mf = 0; mf < 4; ++mf) {
            int mbase = bm * 128 + wm * 64 + mf * 16 + lk * 4;
            #pragma unroll
            for (int r = 0; r < 4; ++r) {
                int mrow = mbase + r;
                pre[((size_t)(mrow >> 7) * N_A + n) * 128 + (mrow & 127)] =
                    f2bf(acc[mf][nf][r] + bias);
            }
        }
    }
}

// ---------------- persistent recurrence kernel ----------------
// 256 blocks (1/CU): bn = bid>>2 (j-group of 16), bm = bid&3 (32 batch rows).
// wh resident in LDS; n/d in registers. Handoff: per-producer flag words
// (plain sc0/sc1 stores, NO atomics), wave-0 parallel poll, h staged via
// batched dwordx4 sc0/sc1 loads (one L3 latency).

__global__ __launch_bounds__(512) void rwa_persist(
    const unsigned short* __restrict__ wh,    // [2048][1024] bf16
    const unsigned short* __restrict__ pre,   // [nt][3072][128] bf16 (this chunk)
    unsigned short* __restrict__ hbuf,        // [2][128][1024] bf16
    float* __restrict__ nbuf, float* __restrict__ dbuf,
    float* __restrict__ out,
    int* __restrict__ flags,                  // flags[bm*64 + bn] = completed steps
    int t0, int nt)
{
    __shared__ unsigned short whs[32][1024];  // 64 KB, resident weights
    __shared__ unsigned short hs[32][1024];   // 64 KB, h staging
    __shared__ float scr[6 * 512];            // 12 KB, k-split reduction

    const int tid = threadIdx.x;
    const int bid = blockIdx.x;
    const int bn = bid >> 2;      // 0..63
    const int bm = bid & 3;       // 0..3
    const int wave = tid >> 6, lane = tid & 63;
    const int wm = wave >> 2;     // 0..1
    const int kq = wave & 3;      // 0..3
    const int lr = lane & 15, lk = lane >> 4;

    // --- load wh tile once (swizzled granules; kernel-boundary coherence) ---
    for (int s = tid; s < 4096; s += 512) {
        int r = s >> 7, g = s & 127;
        uint4 v = *(const uint4*)&wh[(size_t)(bn * 32 + r) * 1024 + (size_t)g * 8];
        *(uint4*)&whs[r][(g ^ (r & 7)) * 8] = v;
    }

    const int j = bn * 16 + lr;
    const int bbase = bm * 32 + wm * 16 + lk * 4;
    float nr[4], dr[4];
    if (kq == 0) {
        #pragma unroll
        for (int r = 0; r < 4; ++r) {
            size_t idx = (size_t)(bbase + r) * D_H + j;
            nr[r] = nbuf[idx]; dr[r] = dbuf[idx];
        }
    }

    // --- precomputed staging geometry: thread -> (rows r0+4i, granule gg) ---
    const int r0 = tid >> 7;              // 0..3
    const int gg = tid & 127;             // 16B granule in row
    const unsigned short* hsrc0 =
        hbuf + (size_t)(bm * 32 + r0) * D_H + (size_t)gg * 8;
    const int* fp = flags + bm * 64 + lane;   // wave-0 poll address
    __syncthreads();

    for (int l = 0; l < nt; ++l) {
        const int t = t0 + l;

        // --- prefetch this step's pre (independent of h; hides HBM latency) ---
        u64 puL = 0, pgL = 0, paL = 0;
        if (kq == 0) {
            size_t pb = (size_t)l * N_A * 128;
            puL = *(const u64*)&pre[pb + ((size_t)j) * 128 + bbase];
            pgL = *(const u64*)&pre[pb + ((size_t)(1024 + j)) * 128 + bbase];
            paL = *(const u64*)&pre[pb + ((size_t)(2048 + j)) * 128 + bbase];
        }

        // --- wait for all 64 producers of this bm group (parallel poll) ---
        if (t > 0) {
            if (wave == 0) {
                for (;;) {
                    int v;
                    asm volatile("global_load_dword %0, %1, off sc0 sc1\n\t"
                                 "s_waitcnt vmcnt(0)"
                                 : "=v"(v) : "v"(fp) : "memory");
                    if (__all(v >= t)) break;
                    __builtin_amdgcn_s_sleep(1);
                }
            }
            __builtin_amdgcn_s_barrier();   // B1: release stagers
        }

        // --- stage h: 8 batched 16B sc0/sc1 loads, one waitcnt, 8 ds_writes ---
        {
            const unsigned short* hsrc = hsrc0 + (size_t)(t & 1) * NB * D_H;
            uint4 v0, v1, v2, v3, v4, v5, v6, v7;
            asm volatile("global_load_dwordx4 %0, %1, off sc0 sc1" : "=v"(v0) : "v"(hsrc)               : "memory");
            asm volatile("global_load_dwordx4 %0, %1, off sc0 sc1" : "=v"(v1) : "v"(hsrc + 4 * D_H)     : "memory");
            asm volatile("global_load_dwordx4 %0, %1, off sc0 sc1" : "=v"(v2) : "v"(hsrc + 8 * D_H)     : "memory");
            asm volatile("global_load_dwordx4 %0, %1, off sc0 sc1" : "=v"(v3) : "v"(hsrc + 12 * D_H)    : "memory");
            asm volatile("global_load_dwordx4 %0, %1, off sc0 sc1" : "=v"(v4) : "v"(hsrc + 16 * D_H)    : "memory");
            asm volatile("global_load_dwordx4 %0, %1, off sc0 sc1" : "=v"(v5) : "v"(hsrc + 20 * D_H)    : "memory");
            asm volatile("global_load_dwordx4 %0, %1, off sc0 sc1" : "=v"(v6) : "v"(hsrc + 24 * D_H)    : "memory");
            asm volatile("global_load_dwordx4 %0, %1, off sc0 sc1" : "=v"(v7) : "v"(hsrc + 28 * D_H)    : "memory");
            asm volatile("s_waitcnt vmcnt(0)" ::: "memory");
            *(uint4*)&hs[r0 +  0][(gg ^ r0) * 8]       = v0;
            *(uint4*)&hs[r0 +  4][(gg ^ r0 ^ 4) * 8]   = v1;
            *(uint4*)&hs[r0 +  8][(gg ^ r0) * 8]       = v2;
            *(uint4*)&hs[r0 + 12][(gg ^ r0 ^ 4) * 8]   = v3;
            *(uint4*)&hs[r0 + 16][(gg ^ r0) * 8]       = v4;
            *(uint4*)&hs[r0 + 20][(gg ^ r0 ^ 4) * 8]   = v5;
            *(uint4*)&hs[r0 + 24][(gg ^ r0) * 8]       = v6;
            *(uint4*)&hs[r0 + 28][(gg ^ r0 ^ 4) * 8]   = v7;
        }
        __syncthreads();   // B2: hs visible

        // --- MFMA: wave kq covers K slice [kq*256, kq*256+256) ---
        f32x4 accg = {}, acca = {};
        const int ar = wm * 16 + lr;
        #pragma unroll
        for (int ks = 0; ks < 8; ++ks) {
            const int k = kq * 256 + ks * 32 + lk * 8;
            const int gidx = k >> 3;
            bf16x8 av = *(const bf16x8*)&hs[ar][(gidx ^ (ar & 7)) << 3];
            bf16x8 bg = *(const bf16x8*)&whs[lr][(gidx ^ (lr & 7)) << 3];
            bf16x8 ba = *(const bf16x8*)&whs[16 + lr][(gidx ^ (lr & 7)) << 3];
            accg = __builtin_amdgcn_mfma_f32_16x16x32_bf16(av, bg, accg, 0, 0, 0);
            acca = __builtin_amdgcn_mfma_f32_16x16x32_bf16(av, ba, acca, 0, 0, 0);
        }

        // --- cross-wave K reduction ---
        if (kq != 0) {
            int base = (wm * 3 + (kq - 1)) * 512 + lane * 4;
            *(f32x4*)&scr[base]       = accg;
            *(f32x4*)&scr[base + 256] = acca;
        }
        __syncthreads();   // B3: scr visible

        if (kq == 0) {
            #pragma unroll
            for (int s = 0; s < 3; ++s) {
                int base = (wm * 3 + s) * 512 + lane * 4;
                accg += *(const f32x4*)&scr[base];
                acca += *(const f32x4*)&scr[base + 256];
            }
            unsigned short* hdst = hbuf + (size_t)((t + 1) & 1) * NB * D_H;
            float hv[4];
            #pragma unroll
            for (int r = 0; r < 4; ++r) {
                float u  = bf2f((unsigned short)(puL >> (16 * r)));
                float gx = bf2f((unsigned short)(pgL >> (16 * r)));
                float ax = bf2f((unsigned short)(paL >> (16 * r)));
                float g = gx + accg[r];
                float a = ax + acca[r];
                float ea = __expf(a);
                float z = u * fast_tanh(g);
                nr[r] += z * ea;
                dr[r] += ea;
                hv[r] = fast_tanh(nr[r] / dr[r]);
                // pack h pair (j even|odd), store sc0/sc1 (L3-coherent)
                unsigned int hb = f2bf(hv[r]);
                unsigned int ob = (unsigned int)__shfl_xor((int)hb, 1);
                if (!(lr & 1)) {
                    unsigned int packed = (hb & 0xffffu) | (ob << 16);
                    unsigned short* hp = hdst + (size_t)(bbase + r) * D_H + j;
                    asm volatile("global_store_dword %0, %1, off sc0 sc1"
                                 :: "v"(hp), "v"(packed) : "memory");
                }
            }
            asm volatile("s_waitcnt vmcnt(0)" ::: "memory");  // h stores acked

            __builtin_amdgcn_s_barrier();   // B4
            if (tid == 0) {
                int done = t + 1;
                asm volatile("global_store_dword %0, %1, off sc0 sc1"
                             :: "v"(flags + bm * 64 + bn), "v"(done) : "memory");
            }
            // out[] HBM stores off the handoff path (drain at next staging)
            #pragma unroll
            for (int r = 0; r < 4; ++r) {
                size_t idx = (size_t)(bbase + r) * D_H + j;
                out[(size_t)t * NB * D_H + idx] = hv[r];
                if (t == T_STEPS - 1) out[(size_t)T_STEPS * NB * D_H + idx] = hv[r];
            }
        } else {
            __builtin_amdgcn_s_barrier();   // B4
        }
    }

    if (kq == 0) {
        #pragma unroll
        for (int r = 0; r < 4; ++r) {
            size_t idx = (size_t)(bbase + r) * D_H + j;
            nbuf[idx] = nr[r]; dbuf[idx] = dr[r];
        }
    }
}

// ---------------- launch ----------------

extern "C" void kernel_launch(void* const* d_in, const int* in_sizes, int n_in,
                              void* d_out, int out_size, void* d_ws, size_t ws_size,
                              hipStream_t stream) {
    const float* x       = (const float*)d_in[0];
    const float* init_st = (const float*)d_in[1];
    const float* uW      = (const float*)d_in[2];
    const float* ub      = (const float*)d_in[3];
    const float* gW      = (const float*)d_in[4];
    const float* gb      = (const float*)d_in[5];
    const float* aW      = (const float*)d_in[6];
    float* out = (float*)d_out;

    char* ws = (char*)d_ws;
    float* nbuf = (float*)ws;                                   ws += (size_t)NB * D_H * 4;
    float* dbuf = (float*)ws;                                   ws += (size_t)NB * D_H * 4;
    unsigned short* hbuf = (unsigned short*)ws;                 ws += (size_t)2 * NB * D_H * 2;
    int* flags = (int*)ws;                                      ws += 256 * 4;
    unsigned short* wa = (unsigned short*)ws;                   ws += (size_t)N_A * D_IN * 2;
    unsigned short* wh = (unsigned short*)ws;                   ws += (size_t)N_H * D_H * 2;
    unsigned short* pre = (unsigned short*)ws;
    size_t fixed = (size_t)(ws - (char*)d_ws);
    size_t per_ct = (size_t)128 * N_A * 2;                      // 768 KB per step slot

    int CT = 1024;
    while (CT > 1 && fixed + (size_t)CT * per_ct > ws_size) CT >>= 1;

    pack_wa<<<(N_A * D_IN + 255) / 256, 256, 0, stream>>>(uW, gW, aW, wa);
    pack_wh<<<(N_H * D_H + 255) / 256, 256, 0, stream>>>(gW, aW, wh);
    rwa_init<<<(NB * D_H + 255) / 256, 256, 0, stream>>>(init_st, nbuf, dbuf, hbuf, flags);

    for (int c = 0; c < T_STEPS / CT; ++c) {
        phase_a<<<dim3(24, CT), 256, 0, stream>>>(
            x + (size_t)c * CT * NB * D_IN, wa, ub, gb, pre);
        rwa_persist<<<256, 512, 0, stream>>>(
            wh, pre, hbuf, nbuf, dbuf, out, flags, c * CT, CT);
    }
}